// Round 2
// baseline (3384.246 us; speedup 1.0000x reference)
//
#include <hip/hip_runtime.h>
#include <cstdint>

typedef unsigned short ushort_t;
typedef short v8s __attribute__((ext_vector_type(8)));
typedef float v4f __attribute__((ext_vector_type(4)));
typedef unsigned short v4u __attribute__((ext_vector_type(4)));

#define DMODEL 1024
#define DFF 4096
#define SEQ 4096
#define NBATCH 4
#define NHEAD 16
#define HDIM 64
#define NLAYER 4
#define MTOK (NBATCH*SEQ)   // 16384

#define EPI_QKV 0
#define EPI_RES 3
#define EPI_GELU 4

__device__ __forceinline__ float bf2f(ushort_t u) {
    unsigned v = ((unsigned)u) << 16; float f; __builtin_memcpy(&f, &v, 4); return f;
}
__device__ __forceinline__ ushort_t f2bf(float f) {
    unsigned u; __builtin_memcpy(&u, &f, 4);
    u = (u + 0x7fffu + ((u >> 16) & 1u)) >> 16;
    return (ushort_t)u;
}

// exact-form GELU with A&S 7.1.26 erf approximation (|err| <= 1.5e-7).
__device__ __forceinline__ float gelu_f(float x) {
    const float y = x * 0.70710678118f;
    const float ay = fabsf(y);
    const float t = __builtin_amdgcn_rcpf(1.f + 0.3275911f * ay);
    const float p = t * (0.254829592f + t * (-0.284496736f + t * (1.421413741f +
                    t * (-1.453152027f + t * 1.061405429f))));
    const float e = __expf(-y * y);
    float er = 1.f - p * e;
    er = (y < 0.f) ? -er : er;
    return 0.5f * x * (1.f + er);
}

// direct global->LDS (16B/lane). LDS dest is wave-uniform base + lane*16.
__device__ __forceinline__ void gload16(const ushort_t* g, ushort_t* l) {
    __builtin_amdgcn_global_load_lds(
        (__attribute__((address_space(1))) unsigned int*)g,
        (__attribute__((address_space(3))) unsigned int*)l, 16, 0, 0);
}

// ---------------------------------------------------------------------------
__global__ __launch_bounds__(256) void cvt_bf16(const float* __restrict__ in,
                                                ushort_t* __restrict__ out, int n) {
    int i = (blockIdx.x * 256 + threadIdx.x) * 4;
    if (i >= n) return;
    float4 v = *(const float4*)(in + i);
    v4u o;
    o[0] = f2bf(v.x); o[1] = f2bf(v.y); o[2] = f2bf(v.z); o[3] = f2bf(v.w);
    *(v4u*)(out + i) = o;
}

// pack Wq/Wk/Wv (each [L][D][D] fp32) into bf16 [L][3][D][D]
__global__ __launch_bounds__(256) void cvt_qkv(const float* __restrict__ Wq,
                                               const float* __restrict__ Wk,
                                               const float* __restrict__ Wv,
                                               ushort_t* __restrict__ out) {
    const size_t DD = (size_t)DMODEL * DMODEL;
    size_t i = ((size_t)blockIdx.x * 256 + threadIdx.x) * 4;
    int l = (int)(i / DD);
    size_t r = i % DD;
    const float* srcs[3] = { Wq + l * DD + r, Wk + l * DD + r, Wv + l * DD + r };
    #pragma unroll
    for (int s = 0; s < 3; s++) {
        float4 v = *(const float4*)srcs[s];
        v4u o;
        o[0] = f2bf(v.x); o[1] = f2bf(v.y); o[2] = f2bf(v.z); o[3] = f2bf(v.w);
        *(v4u*)(out + ((size_t)l * 3 + s) * DD + r) = o;
    }
}

// ---------------------------------------------------------------------------
__global__ __launch_bounds__(256) void lens_kernel(const unsigned char* __restrict__ mask,
                                                   int* __restrict__ lens) {
    int lane = threadIdx.x & 63, w = threadIdx.x >> 6;
    int cnt = 0;
    for (int i = lane; i < SEQ; i += 64) cnt += (mask[w * SEQ + i] != 0) ? 1 : 0;
    #pragma unroll
    for (int off = 32; off; off >>= 1) cnt += __shfl_down(cnt, off);
    if (lane == 0) lens[w] = SEQ - cnt;
}

// ---------------------------------------------------------------------------
// GEMM: C[M,N] = A[M,K] @ B[N,K]^T, bf16 in, fp32 acc, fused epilogues.
// 256x256 tile, BK=64, 8 waves of 128x64 each (512 threads), 8-phase-style
// schedule (learn_hip m201 template, T2+T3+T4+T5):
//  - global_load_lds (16B) staging, LDS linear dest + XOR-pre-swizzled global
//    source; ds_read side applies the same XOR -> 0 bank conflicts.
//  - 4 compute phases per K-tile (one 32-row quadrant x K=64 = 16 MFMA each),
//    raw s_barrier pairs per phase (NO __syncthreads -> no vmcnt(0) drain).
//  - counted vmcnt: tile t+2's 8 loads are issued inside phase 3 of tile t
//    (after the mid-barrier fencing all of tile t's ds_reads), end-of-tile
//    wait is vmcnt(8) -> loads never fully drain in steady state.
//  - s_setprio(1) around each MFMA cluster (T5).
// LDS 128 KiB (2 bufs x (A 32K + B 32K)) -> 1 block/CU, 2 waves/SIMD.
// ---------------------------------------------------------------------------
#define BAR()    asm volatile("s_barrier" ::: "memory")
#define WAITL0() asm volatile("s_waitcnt lgkmcnt(0)" ::: "memory")
#define WAITV8() asm volatile("s_waitcnt vmcnt(8)" ::: "memory")
#define WAITV0() asm volatile("s_waitcnt vmcnt(0)" ::: "memory")

template <int EPI>
__global__ __launch_bounds__(512, 2) void gemm_bt(
    const ushort_t* __restrict__ A, const ushort_t* __restrict__ B,
    const float* __restrict__ bias, const float* __restrict__ bias2,
    const float* __restrict__ bias3, const float* res,
    const int* __restrict__ lens,
    ushort_t* __restrict__ outB, ushort_t* __restrict__ outB2,
    ushort_t* __restrict__ outB3, float* outF,
    int M, int N, int K)
{
    __shared__ __align__(16) ushort_t As[2][256 * 64];
    __shared__ __align__(16) ushort_t Bs[2][256 * 64];

    const int tid = threadIdx.x;
    const int lane = tid & 63;
    const int w = tid >> 6;          // 0..7
    const int wm = w >> 2;           // 0..1 : row half (128 rows)
    const int wn = w & 3;            // 0..3 : col quarter (64 cols)
    const int nb = N >> 8;
    // XCD-aware remap (dispatch round-robins XCD = blockIdx.x % 8)
    const int xcd = blockIdx.x & 7;
    const int q = blockIdx.x >> 3;
    const int bm = (q / nb) * 8 + xcd;   // M/256 = 64, divisible by 8
    const int bn = q % nb;
    const int lr = lane & 15;
    const int lq = lane >> 4;  // 0..3

    v4f acc[8][4];
    #pragma unroll
    for (int i = 0; i < 8; i++)
        #pragma unroll
        for (int j = 0; j < 4; j++) acc[i][j] = (v4f)0.f;

    // ---- staging geometry ---------------------------------------------
    // A tile = 256 rows x 64 k (row-major, 8 chunks of 8 bf16 per row).
    // LDS slot s of row r holds global chunk s ^ (r&7)  (bank-spread XOR).
    // gload_lds writes LDS linearly (base + lane*16B), so the XOR is applied
    // to the per-lane GLOBAL source address instead:
    //   wave-chunk c (1024B) covers rows c*8..c*8+7; lane l -> row c*8+(l>>3),
    //   slot l&7  => global chunk (l&7)^(l>>3).
    const int srow = lane >> 3;            // 0..7
    const int schunk = (lane & 7) ^ srow;  // pre-swizzled source chunk
    const ushort_t* Ag = A + (size_t)(bm * 256 + srow) * K + schunk * 8;
    const ushort_t* Bg = B + (size_t)(bn * 256 + srow) * K + schunk * 8;

    // ---- read-side fragment offsets (k-invariant, read-side XOR) ------
    // A frag (quad qq, rowfrag i, khalf kh): row ra = wm*128+qq*32+i*16+lr,
    // global chunk kh*4+lq, LDS slot (kh*4+lq)^(ra&7); ra&7 == lr&7.
    int aoff[2], boff[2];
    #pragma unroll
    for (int kh = 0; kh < 2; kh++) {
        aoff[kh] = (wm * 128 + lr) * 64 + (((kh * 4 + lq) ^ (lr & 7)) * 8);
        boff[kh] = (wn * 64 + lr) * 64 + (((kh * 4 + lq) ^ (lr & 7)) * 8);
    }

    const int KT = K >> 6;

#define ISSUE_TILE(T_, P_) do { \
    const size_t kk_ = (size_t)(T_) << 6; \
    _Pragma("unroll") \
    for (int i_ = 0; i_ < 4; i_++) { \
        const int c_ = (w << 2) + i_; \
        gload16(Ag + (size_t)c_ * 8 * K + kk_, &As[P_][c_ << 9]); \
        gload16(Bg + (size_t)c_ * 8 * K + kk_, &Bs[P_][c_ << 9]); \
    } \
} while (0)

#define READ_B(P_) do { \
    _Pragma("unroll") \
    for (int j_ = 0; j_ < 4; j_++) \
        _Pragma("unroll") \
        for (int kh_ = 0; kh_ < 2; kh_++) \
            bfr[j_][kh_] = *(const v8s*)&Bs[P_][boff[kh_] + j_ * 1024]; \
} while (0)

#define READ_A(P_, QQ) do { \
    _Pragma("unroll") \
    for (int i_ = 0; i_ < 2; i_++) \
        _Pragma("unroll") \
        for (int kh_ = 0; kh_ < 2; kh_++) \
            af[i_][kh_] = *(const v8s*)&As[P_][aoff[kh_] + (QQ) * 2048 + i_ * 1024]; \
} while (0)

#define MFMA_PHASE(QQ) do { \
    BAR(); WAITL0(); \
    __builtin_amdgcn_s_setprio(1); \
    _Pragma("unroll") \
    for (int i_ = 0; i_ < 2; i_++) \
        _Pragma("unroll") \
        for (int j_ = 0; j_ < 4; j_++) \
            _Pragma("unroll") \
            for (int kh_ = 0; kh_ < 2; kh_++) \
                acc[(QQ) * 2 + i_][j_] = __builtin_amdgcn_mfma_f32_16x16x32_bf16( \
                    af[i_][kh_], bfr[j_][kh_], acc[(QQ) * 2 + i_][j_], 0, 0, 0); \
    __builtin_amdgcn_s_setprio(0); \
} while (0)

// one K-tile: phases 0..3 (quadrants), issue t+2 inside phase 3 after the
// mid-barrier (which fences every wave's last ds_read of this tile), then
// counted vmcnt(8) -> tile t+1 landed, t+2's 8 loads stay in flight.
#define TILE_BODY(T_, P_) do { \
    v8s af[2][2]; v8s bfr[4][2]; \
    READ_B(P_); READ_A(P_, 0); \
    MFMA_PHASE(0); BAR(); \
    READ_A(P_, 1); MFMA_PHASE(1); BAR(); \
    READ_A(P_, 2); MFMA_PHASE(2); BAR(); \
    READ_A(P_, 3); MFMA_PHASE(3); \
    if ((T_) + 2 < KT) { ISSUE_TILE((T_) + 2, P_); WAITV8(); } \
    else if ((T_) + 1 < KT) { WAITV0(); } \
    BAR(); \
} while (0)

    // prologue: tiles 0 and 1 in flight; wait tile 0 only.
    ISSUE_TILE(0, 0);
    ISSUE_TILE(1, 1);
    WAITV8();
    BAR();

    for (int t = 0; t < KT; t += 2) {   // KT is even (K = 1024 or 4096)
        TILE_BODY(t, 0);
        TILE_BODY(t + 1, 1);
    }

#undef TILE_BODY
#undef MFMA_PHASE
#undef READ_A
#undef READ_B
#undef ISSUE_TILE

    // epilogue: C/D layout col = lane&15, row = (lane>>4)*4 + reg
    const int row0 = bm * 256 + wm * 128 + lq * 4;
    const int col0 = bn * 256 + wn * 64 + lr;

    const int seg = (EPI == EPI_QKV) ? (bn >> 2) : 0;   // 1024-col segments
    ushort_t* qkv_out = (EPI == EPI_QKV)
        ? (seg == 0 ? outB : (seg == 1 ? outB2 : outB3)) : outB;
    const float* qkv_bias = (EPI == EPI_QKV)
        ? (seg == 0 ? bias : (seg == 1 ? bias2 : bias3)) : bias;
    const int blen = (EPI == EPI_QKV) ? lens[bm >> 4] : 0;

    #pragma unroll
    for (int i = 0; i < 8; i++) {
        #pragma unroll
        for (int j = 0; j < 4; j++) {
            const int gn = col0 + j * 16;
            const float bsv = (EPI == EPI_QKV) ? qkv_bias[gn & 1023] : bias[gn];
            #pragma unroll
            for (int r = 0; r < 4; r++) {
                const int gm = row0 + i * 16 + r;
                float v = acc[i][j][r] + bsv;
                if (EPI == EPI_QKV) {
                    const size_t oi = (size_t)gm * DMODEL + (gn & 1023);
                    if (seg == 2) {
                        qkv_out[oi] = f2bf(v);                    // V
                    } else {
                        float e = v > 0.f ? v + 1.f : __expf(v);  // elu+1
                        if (seg == 1 && (gm & 4095) >= blen) e = 0.f;  // K mask
                        qkv_out[oi] = f2bf(e);
                    }
                } else if (EPI == EPI_RES) {
                    const size_t oi = (size_t)gm * N + gn;
                    outF[oi] = v + res[oi];
                } else {  // EPI_GELU
                    const size_t oi = (size_t)gm * N + gn;
                    outB[oi] = f2bf(gelu_f(v));
                }
            }
        }
    }
}

// ---------------------------------------------------------------------------
__global__ __launch_bounds__(256) void ksum_kernel(const ushort_t* __restrict__ K,
                                                   float* __restrict__ out) {
    const int blk = blockIdx.x;
    const int n = blk >> 4, cg = blk & 15;
    const int tx = threadIdx.x & 63, ty = threadIdx.x >> 6;
    const int col = cg * 64 + tx;
    const ushort_t* p = K + ((size_t)n * SEQ + ty * 1024) * DMODEL + col;
    float a = 0.f;
    for (int s = 0; s < 1024; s++) a += bf2f(p[(size_t)s * DMODEL]);
    __shared__ float red[4][64];
    red[ty][tx] = a;
    __syncthreads();
    if (ty == 0) out[n * DMODEL + col] = red[0][tx] + red[1][tx] + red[2][tx] + red[3][tx];
}

// ---------------------------------------------------------------------------
__global__ __launch_bounds__(256) void kv_part(const ushort_t* __restrict__ K,
                                               const ushort_t* __restrict__ V,
                                               float* __restrict__ part) {
    const int chunk = blockIdx.x, nh = blockIdx.y;
    const int n = nh >> 4, h = nh & 15;
    const int tid = threadIdx.x;
    const int tm = tid >> 4, td = tid & 15;
    __shared__ float Ks[16][68];
    __shared__ float Vs[16][68];
    float acc[4][4] = {};
    const int s0 = chunk * 512;
    for (int sb = 0; sb < 512; sb += 16) {
        __syncthreads();
        for (int idx = tid; idx < 1024; idx += 256) {
            const int r = idx >> 6, c = idx & 63;
            const size_t gpos = ((size_t)(n * SEQ + s0 + sb + r)) * DMODEL + h * HDIM + c;
            Ks[r][c] = bf2f(K[gpos]);
            Vs[r][c] = bf2f(V[gpos]);
        }
        __syncthreads();
        #pragma unroll
        for (int s = 0; s < 16; s++) {
            float kv[4], vv[4];
            #pragma unroll
            for (int j = 0; j < 4; j++) kv[j] = Ks[s][td * 4 + j];
            #pragma unroll
            for (int i = 0; i < 4; i++) vv[i] = Vs[s][tm * 4 + i];
            #pragma unroll
            for (int i = 0; i < 4; i++)
                #pragma unroll
                for (int j = 0; j < 4; j++)
                    acc[i][j] += vv[i] * kv[j];
        }
    }
    float* o = part + ((size_t)chunk * 64 + nh) * 4096;
    #pragma unroll
    for (int i = 0; i < 4; i++)
        #pragma unroll
        for (int j = 0; j < 4; j++)
            o[(tm * 4 + i) * 64 + td * 4 + j] = acc[i][j];
}

__global__ __launch_bounds__(256) void kv_reduce(const float* __restrict__ part,
                                                 float* __restrict__ KV) {
    const int gid = blockIdx.x * 256 + threadIdx.x;
    float a = 0.f;
    #pragma unroll
    for (int c = 0; c < 8; c++) a += part[(size_t)c * (64 * 4096) + gid];
    KV[gid] = a;
}

// ---------------------------------------------------------------------------
__global__ __launch_bounds__(256) void attn_kernel(const ushort_t* __restrict__ Q,
                                                   const float* __restrict__ KV,
                                                   const float* __restrict__ Ksum,
                                                   ushort_t* __restrict__ out) {
    const int bx = blockIdx.x, nh = blockIdx.y;
    const int n = nh >> 4, h = nh & 15;
    const int tid = threadIdx.x;
    const int ty = tid >> 4, tx = tid & 15;
    __shared__ float KVs[64][65];
    __shared__ float Qs[64][65];
    __shared__ float Zs[64];
    const int t0 = n * SEQ + bx * 64;
    for (int idx = tid; idx < 4096; idx += 256) {
        const int r = idx >> 6, c = idx & 63;
        KVs[r][c] = KV[(size_t)nh * 4096 + idx];
        Qs[r][c] = bf2f(Q[((size_t)(t0 + r)) * DMODEL + h * HDIM + c]);
    }
    __syncthreads();
    if (tid < 64) {
        const float* ks = Ksum + n * DMODEL + h * HDIM;
        float a = 0.f;
        #pragma unroll
        for (int d = 0; d < 64; d++) a += Qs[tid][d] * ks[d];
        Zs[tid] = 1.f / (a + 1e-6f);
    }
    __syncthreads();
    float acc[4][4] = {};
    for (int d = 0; d < 64; d++) {
        float qv[4], kv[4];
        #pragma unroll
        for (int i = 0; i < 4; i++) qv[i] = Qs[ty * 4 + i][d];
        #pragma unroll
        for (int j = 0; j < 4; j++) kv[j] = KVs[tx * 4 + j][d];
        #pragma unroll
        for (int i = 0; i < 4; i++)
            #pragma unroll
            for (int j = 0; j < 4; j++)
                acc[i][j] += qv[i] * kv[j];
    }
    #pragma unroll
    for (int i = 0; i < 4; i++) {
        const int r = ty * 4 + i;
        const float z = Zs[r];
        v4u o;
        #pragma unroll
        for (int j = 0; j < 4; j++) o[j] = f2bf(acc[i][j] * z);
        *(v4u*)&out[((size_t)(t0 + r)) * DMODEL + h * HDIM + tx * 4] = o;  // 8B store
    }
}

// ---------------------------------------------------------------------------
__global__ __launch_bounds__(256) void ln_kernel(const float* in, float* outF,
                                                 ushort_t* outB,
                                                 const float* __restrict__ g,
                                                 const float* __restrict__ b) {
    const int row = blockIdx.x;
    const int tid = threadIdx.x;
    const float4 v = ((const float4*)(in + (size_t)row * DMODEL))[tid];
    float s = v.x + v.y + v.z + v.w;
    float ss = v.x * v.x + v.y * v.y + v.z * v.z + v.w * v.w;
    #pragma unroll
    for (int off = 32; off; off >>= 1) {
        s += __shfl_down(s, off);
        ss += __shfl_down(ss, off);
    }
    __shared__ float red[8];
    const int lane = tid & 63, w = tid >> 6;
    if (lane == 0) { red[w * 2] = s; red[w * 2 + 1] = ss; }
    __syncthreads();
    s = red[0] + red[2] + red[4] + red[6];
    ss = red[1] + red[3] + red[5] + red[7];
    const float mu = s * (1.f / DMODEL);
    const float var = ss * (1.f / DMODEL) - mu * mu;
    const float rs = rsqrtf(var + 1e-5f);
    const float4 gg = ((const float4*)g)[tid];
    const float4 bb = ((const float4*)b)[tid];
    float4 o;
    o.x = (v.x - mu) * rs * gg.x + bb.x;
    o.y = (v.y - mu) * rs * gg.y + bb.y;
    o.z = (v.z - mu) * rs * gg.z + bb.z;
    o.w = (v.w - mu) * rs * gg.w + bb.w;
    ((float4*)(outF + (size_t)row * DMODEL))[tid] = o;
    if (outB) {
        v4u ob;
        ob[0] = f2bf(o.x); ob[1] = f2bf(o.y); ob[2] = f2bf(o.z); ob[3] = f2bf(o.w);
        *(v4u*)(outB + (size_t)row * DMODEL + tid * 4) = ob;
    }
}

// ---------------------------------------------------------------------------
extern "C" void kernel_launch(void* const* d_in, const int* in_sizes, int n_in,
                              void* d_out, int out_size, void* d_ws, size_t ws_size,
                              hipStream_t stream) {
    const float* src = (const float*)d_in[0];
    const unsigned char* mask = (const unsigned char*)d_in[1];
    const float* Wq = (const float*)d_in[2];
    const float* bq = (const float*)d_in[3];
    const float* Wk = (const float*)d_in[4];
    const float* bk = (const float*)d_in[5];
    const float* Wv = (const float*)d_in[6];
    const float* bv = (const float*)d_in[7];
    const float* Wo = (const float*)d_in[8];
    const float* bo = (const float*)d_in[9];
    const float* W1 = (const float*)d_in[10];
    const float* b1 = (const float*)d_in[11];
    const float* W2 = (const float*)d_in[12];
    const float* b2 = (const float*)d_in[13];
    const float* g1 = (const float*)d_in[14];
    const float* be1 = (const float*)d_in[15];
    const float* g2 = (const float*)d_in[16];
    const float* be2 = (const float*)d_in[17];

    float* xout = (float*)d_out;  // fp32 residual-stream master

    char* ws = (char*)d_ws;
    size_t off = 0;
    auto alloc = [&](size_t bytes) -> void* {
        void* p = (void*)(ws + off);
        off += (bytes + 255) & ~(size_t)255;
        return p;
    };
    const size_t DD = (size_t)DMODEL * DMODEL;
    const size_t FD = (size_t)DFF * DMODEL;
    const size_t MD = (size_t)MTOK * DMODEL;

    ushort_t* wqkv_bf = (ushort_t*)alloc(NLAYER * 3 * DD * 2);  // [L][3][D][D]
    ushort_t* wo_bf = (ushort_t*)alloc(NLAYER * DD * 2);
    ushort_t* w1r = (ushort_t*)alloc(FD * 2);
    ushort_t* w2r = (ushort_t*)alloc(FD * 2);
    ushort_t* xbf = (ushort_t*)alloc(MD * 2);
    ushort_t* Qb = (ushort_t*)alloc(MD * 2);
    ushort_t* Kb = (ushort_t*)alloc(MD * 2);
    ushort_t* Vb = (ushort_t*)alloc(MD * 2);
    (void)alloc(MD * 2);          // hb (=Qb) overlay spans MTOK*DFF bf16
    ushort_t* hb = Qb;
    float* Ksum = (float*)alloc((size_t)NBATCH * DMODEL * 4);
    float* KVp = (float*)alloc((size_t)8 * 64 * 4096 * 4);
    float* KVb = (float*)alloc((size_t)64 * 4096 * 4);
    int* lens = (int*)alloc(256);
    if (off > ws_size) return;

    cvt_qkv<<<dim3((unsigned)((NLAYER * DD) / 1024)), dim3(256), 0, stream>>>(Wq, Wk, Wv, wqkv_bf);
    cvt_bf16<<<dim3((unsigned)((NLAYER * DD) / 1024)), dim3(256), 0, stream>>>(Wo, wo_bf, (int)(NLAYER * DD));
    lens_kernel<<<dim3(1), dim3(256), 0, stream>>>(mask, lens);
    cvt_bf16<<<dim3((unsigned)(MD / 1024)), dim3(256), 0, stream>>>(src, xbf, (int)MD);

    const dim3 blk(256);
    const dim3 blkG(512);
    const dim3 gQKV((MTOK / 256) * (3 * DMODEL / 256));  // 768 blocks
    const dim3 gD((MTOK / 256) * (DMODEL / 256));        // 256 blocks
    const dim3 gF((MTOK / 256) * (DFF / 256));           // 1024 blocks

    for (int l = 0; l < NLAYER; l++) {
        const ushort_t* wqkvl = wqkv_bf + (size_t)l * 3 * DD;
        const ushort_t* wol = wo_bf + l * DD;
        const float* bql = bq + l * DMODEL;
        const float* bkl = bk + l * DMODEL;
        const float* bvl = bv + l * DMODEL;
        const float* bol = bo + l * DMODEL;
        const float* b1l = b1 + l * DFF;
        const float* b2l = b2 + l * DMODEL;
        const float* g1l = g1 + l * DMODEL;
        const float* be1l = be1 + l * DMODEL;
        const float* g2l = g2 + l * DMODEL;
        const float* be2l = be2 + l * DMODEL;
        const float* resx = (l == 0) ? src : xout;

        // fused Q/K/V projection with feature map + mask
        gemm_bt<EPI_QKV><<<gQKV, blkG, 0, stream>>>(xbf, wqkvl, bql, bkl, bvl,
            nullptr, lens, Qb, Kb, Vb, nullptr, MTOK, 3 * DMODEL, DMODEL);

        // linear-attention core
        ksum_kernel<<<dim3(64), blk, 0, stream>>>(Kb, Ksum);
        kv_part<<<dim3(8, 64), blk, 0, stream>>>(Kb, Vb, KVp);
        kv_reduce<<<dim3(64 * 4096 / 256), blk, 0, stream>>>(KVp, KVb);
        attn_kernel<<<dim3(64, 64), blk, 0, stream>>>(Qb, KVb, Ksum, Kb);  // attn -> Kb

        // output projection + residual (fp32), then LN1 + bf16 copy
        gemm_bt<EPI_RES><<<gD, blkG, 0, stream>>>(Kb, wol, bol, nullptr, nullptr,
            resx, lens, nullptr, nullptr, nullptr, xout, MTOK, DMODEL, DMODEL);
        ln_kernel<<<dim3(MTOK), blk, 0, stream>>>(xout, xout, xbf, g1l, be1l);

        // FFN
        cvt_bf16<<<dim3((unsigned)(FD / 1024)), blk, 0, stream>>>(W1 + l * FD, w1r, (int)FD);
        gemm_bt<EPI_GELU><<<gF, blkG, 0, stream>>>(xbf, w1r, b1l, nullptr, nullptr,
            nullptr, lens, hb, nullptr, nullptr, nullptr, MTOK, DFF, DMODEL);
        cvt_bf16<<<dim3((unsigned)(FD / 1024)), blk, 0, stream>>>(W2 + l * FD, w2r, (int)FD);
        gemm_bt<EPI_RES><<<gD, blkG, 0, stream>>>(hb, w2r, b2l, nullptr, nullptr,
            xout, lens, nullptr, nullptr, nullptr, xout, MTOK, DMODEL, DFF);
        ln_kernel<<<dim3(MTOK), blk, 0, stream>>>(xout, xout, (l == NLAYER - 1) ? nullptr : xbf, g2l, be2l);
    }
}

// Round 3
// 3086.388 us; speedup vs baseline: 1.0965x; 1.0965x over previous
//
#include <hip/hip_runtime.h>
#include <cstdint>

typedef unsigned short ushort_t;
typedef short v8s __attribute__((ext_vector_type(8)));
typedef float v4f __attribute__((ext_vector_type(4)));
typedef unsigned short v4u __attribute__((ext_vector_type(4)));

#define DMODEL 1024
#define DFF 4096
#define SEQ 4096
#define NBATCH 4
#define NHEAD 16
#define HDIM 64
#define NLAYER 4
#define MTOK (NBATCH*SEQ)   // 16384

#define EPI_QKV 0
#define EPI_RES 3
#define EPI_GELU 4

__device__ __forceinline__ float bf2f(ushort_t u) {
    unsigned v = ((unsigned)u) << 16; float f; __builtin_memcpy(&f, &v, 4); return f;
}
__device__ __forceinline__ ushort_t f2bf(float f) {
    unsigned u; __builtin_memcpy(&u, &f, 4);
    u = (u + 0x7fffu + ((u >> 16) & 1u)) >> 16;
    return (ushort_t)u;
}

// exact-form GELU with A&S 7.1.26 erf approximation (|err| <= 1.5e-7).
__device__ __forceinline__ float gelu_f(float x) {
    const float y = x * 0.70710678118f;
    const float ay = fabsf(y);
    const float t = __builtin_amdgcn_rcpf(1.f + 0.3275911f * ay);
    const float p = t * (0.254829592f + t * (-0.284496736f + t * (1.421413741f +
                    t * (-1.453152027f + t * 1.061405429f))));
    const float e = __expf(-y * y);
    float er = 1.f - p * e;
    er = (y < 0.f) ? -er : er;
    return 0.5f * x * (1.f + er);
}

// direct global->LDS (16B/lane). LDS dest is wave-uniform base + lane*16.
__device__ __forceinline__ void gload16(const ushort_t* g, ushort_t* l) {
    __builtin_amdgcn_global_load_lds(
        (__attribute__((address_space(1))) unsigned int*)g,
        (__attribute__((address_space(3))) unsigned int*)l, 16, 0, 0);
}

// ---------------------------------------------------------------------------
__global__ __launch_bounds__(256) void cvt_bf16(const float* __restrict__ in,
                                                ushort_t* __restrict__ out, int n) {
    int i = (blockIdx.x * 256 + threadIdx.x) * 4;
    if (i >= n) return;
    float4 v = *(const float4*)(in + i);
    v4u o;
    o[0] = f2bf(v.x); o[1] = f2bf(v.y); o[2] = f2bf(v.z); o[3] = f2bf(v.w);
    *(v4u*)(out + i) = o;
}

// pack Wq/Wk/Wv (each [L][D][D] fp32) into bf16 [L][3][D][D]
__global__ __launch_bounds__(256) void cvt_qkv(const float* __restrict__ Wq,
                                               const float* __restrict__ Wk,
                                               const float* __restrict__ Wv,
                                               ushort_t* __restrict__ out) {
    const size_t DD = (size_t)DMODEL * DMODEL;
    size_t i = ((size_t)blockIdx.x * 256 + threadIdx.x) * 4;
    int l = (int)(i / DD);
    size_t r = i % DD;
    const float* srcs[3] = { Wq + l * DD + r, Wk + l * DD + r, Wv + l * DD + r };
    #pragma unroll
    for (int s = 0; s < 3; s++) {
        float4 v = *(const float4*)srcs[s];
        v4u o;
        o[0] = f2bf(v.x); o[1] = f2bf(v.y); o[2] = f2bf(v.z); o[3] = f2bf(v.w);
        *(v4u*)(out + ((size_t)l * 3 + s) * DD + r) = o;
    }
}

// ---------------------------------------------------------------------------
__global__ __launch_bounds__(256) void lens_kernel(const unsigned char* __restrict__ mask,
                                                   int* __restrict__ lens) {
    int lane = threadIdx.x & 63, w = threadIdx.x >> 6;
    int cnt = 0;
    for (int i = lane; i < SEQ; i += 64) cnt += (mask[w * SEQ + i] != 0) ? 1 : 0;
    #pragma unroll
    for (int off = 32; off; off >>= 1) cnt += __shfl_down(cnt, off);
    if (lane == 0) lens[w] = SEQ - cnt;
}

// ---------------------------------------------------------------------------
// GEMM: C[M,N] = A[M,K] @ B[N,K]^T, bf16 in, fp32 acc, fused epilogues.
// 256x256 tile, BK=64, 8 waves of 128x64 each (512 threads).
// R3 schedule: counted-lgkm pipeline, 2 barriers per K-tile (was 8).
//  - Within a K-tile all quads only READ the LDS buffer -> no intra-tile
//    barriers. A-quad q+1 ds_reads are issued BEFORE quad q's MFMA; the
//    compiler's counted lgkmcnt(N) overlaps reads with MFMA (m97 behavior).
//  - Buffer-overwrite protection: lgkmcnt(0)+s_barrier BEFORE ISSUE_TILE
//    (all waves' reads COMPLETE, not just issued). MFMA quad 3 sits between
//    ISSUE and the vmcnt wait to cover the gload issue.
//  - counted vmcnt(8): tile t+1's loads confirmed, tile t+2's stay in flight
//    across the barrier (never drains to 0 in steady state).
//  - s_setprio(1) around each MFMA cluster (T5).
// global_load_lds staging, LDS linear dest + XOR-pre-swizzled global source;
// read side applies the same XOR -> 0 bank conflicts (verified R2).
// LDS 128 KiB -> 1 block/CU, 2 waves/SIMD.
// ---------------------------------------------------------------------------
#define BAR()    asm volatile("s_barrier" ::: "memory")
#define WAITL0() asm volatile("s_waitcnt lgkmcnt(0)" ::: "memory")
#define WAITV8() asm volatile("s_waitcnt vmcnt(8)" ::: "memory")
#define WAITV0() asm volatile("s_waitcnt vmcnt(0)" ::: "memory")

template <int EPI>
__global__ __launch_bounds__(512, 2) void gemm_bt(
    const ushort_t* __restrict__ A, const ushort_t* __restrict__ B,
    const float* __restrict__ bias, const float* __restrict__ bias2,
    const float* __restrict__ bias3, const float* res,
    const int* __restrict__ lens,
    ushort_t* __restrict__ outB, ushort_t* __restrict__ outB2,
    ushort_t* __restrict__ outB3, float* outF,
    int M, int N, int K)
{
    __shared__ __align__(16) ushort_t As[2][256 * 64];
    __shared__ __align__(16) ushort_t Bs[2][256 * 64];

    const int tid = threadIdx.x;
    const int lane = tid & 63;
    const int w = tid >> 6;          // 0..7
    const int wm = w >> 2;           // 0..1 : row half (128 rows)
    const int wn = w & 3;            // 0..3 : col quarter (64 cols)
    const int nb = N >> 8;
    // XCD-aware remap (dispatch round-robins XCD = blockIdx.x % 8)
    const int xcd = blockIdx.x & 7;
    const int q = blockIdx.x >> 3;
    const int bm = (q / nb) * 8 + xcd;   // M/256 = 64, divisible by 8
    const int bn = q % nb;
    const int lr = lane & 15;
    const int lq = lane >> 4;  // 0..3

    v4f acc[8][4];
    #pragma unroll
    for (int i = 0; i < 8; i++)
        #pragma unroll
        for (int j = 0; j < 4; j++) acc[i][j] = (v4f)0.f;

    // ---- staging geometry ---------------------------------------------
    // A tile = 256 rows x 64 k (row-major, 8 chunks of 8 bf16 per row).
    // LDS slot s of row r holds global chunk s ^ (r&7)  (bank-spread XOR).
    // gload_lds writes LDS linearly (base + lane*16B), so the XOR is applied
    // to the per-lane GLOBAL source address instead:
    //   wave-chunk c (1024B) covers rows c*8..c*8+7; lane l -> row c*8+(l>>3),
    //   slot l&7  => global chunk (l&7)^(l>>3).
    const int srow = lane >> 3;            // 0..7
    const int schunk = (lane & 7) ^ srow;  // pre-swizzled source chunk
    const ushort_t* Ag = A + (size_t)(bm * 256 + srow) * K + schunk * 8;
    const ushort_t* Bg = B + (size_t)(bn * 256 + srow) * K + schunk * 8;

    // ---- read-side fragment offsets (k-invariant, read-side XOR) ------
    // A frag (quad qq, rowfrag i, khalf kh): row ra = wm*128+qq*32+i*16+lr,
    // global chunk kh*4+lq, LDS slot (kh*4+lq)^(ra&7); ra&7 == lr&7.
    int aoff[2], boff[2];
    #pragma unroll
    for (int kh = 0; kh < 2; kh++) {
        aoff[kh] = (wm * 128 + lr) * 64 + (((kh * 4 + lq) ^ (lr & 7)) * 8);
        boff[kh] = (wn * 64 + lr) * 64 + (((kh * 4 + lq) ^ (lr & 7)) * 8);
    }

    const int KT = K >> 6;

#define ISSUE_TILE(T_, P_) do { \
    const size_t kk_ = (size_t)(T_) << 6; \
    _Pragma("unroll") \
    for (int i_ = 0; i_ < 4; i_++) { \
        const int c_ = (w << 2) + i_; \
        gload16(Ag + (size_t)c_ * 8 * K + kk_, &As[P_][c_ << 9]); \
        gload16(Bg + (size_t)c_ * 8 * K + kk_, &Bs[P_][c_ << 9]); \
    } \
} while (0)

#define READ_B(P_) do { \
    _Pragma("unroll") \
    for (int j_ = 0; j_ < 4; j_++) \
        _Pragma("unroll") \
        for (int kh_ = 0; kh_ < 2; kh_++) \
            bfr[j_][kh_] = *(const v8s*)&Bs[P_][boff[kh_] + j_ * 1024]; \
} while (0)

#define READ_AQ(P_, QQ, AF) do { \
    _Pragma("unroll") \
    for (int i_ = 0; i_ < 2; i_++) \
        _Pragma("unroll") \
        for (int kh_ = 0; kh_ < 2; kh_++) \
            AF[i_][kh_] = *(const v8s*)&As[P_][aoff[kh_] + (QQ) * 2048 + i_ * 1024]; \
} while (0)

#define MFMA_Q(QQ, AF) do { \
    __builtin_amdgcn_s_setprio(1); \
    _Pragma("unroll") \
    for (int i_ = 0; i_ < 2; i_++) \
        _Pragma("unroll") \
        for (int j_ = 0; j_ < 4; j_++) \
            _Pragma("unroll") \
            for (int kh_ = 0; kh_ < 2; kh_++) \
                acc[(QQ) * 2 + i_][j_] = __builtin_amdgcn_mfma_f32_16x16x32_bf16( \
                    AF[i_][kh_], bfr[j_][kh_], acc[(QQ) * 2 + i_][j_], 0, 0, 0); \
    __builtin_amdgcn_s_setprio(0); \
} while (0)

// one K-tile, counted-lgkm pipeline, 2 barriers total.
#define TILE_BODY(T_, P_) do { \
    v8s bfr[4][2]; \
    v8s af0[2][2], af1[2][2], af2[2][2], af3[2][2]; \
    READ_B(P_); \
    READ_AQ(P_, 0, af0); \
    READ_AQ(P_, 1, af1); \
    MFMA_Q(0, af0); \
    READ_AQ(P_, 2, af2); \
    MFMA_Q(1, af1); \
    READ_AQ(P_, 3, af3); \
    MFMA_Q(2, af2); \
    WAITL0(); \
    if ((T_) + 2 < KT) { \
        BAR();                       /* all waves' reads of buf P_ complete */ \
        ISSUE_TILE((T_) + 2, P_); \
        MFMA_Q(3, af3); \
        WAITV8();                    /* tile t+1 landed; t+2 stays in flight */ \
        BAR(); \
    } else if ((T_) + 1 < KT) { \
        MFMA_Q(3, af3); \
        WAITV0(); \
        BAR(); \
    } else { \
        MFMA_Q(3, af3); \
    } \
} while (0)

    // prologue: tiles 0 and 1 in flight; wait tile 0 only.
    ISSUE_TILE(0, 0);
    ISSUE_TILE(1, 1);
    WAITV8();
    BAR();

    for (int t = 0; t < KT; t += 2) {   // KT is even (K = 1024 or 4096)
        TILE_BODY(t, 0);
        TILE_BODY(t + 1, 1);
    }

#undef TILE_BODY
#undef MFMA_Q
#undef READ_AQ
#undef READ_B
#undef ISSUE_TILE

    // epilogue: C/D layout col = lane&15, row = (lane>>4)*4 + reg
    const int row0 = bm * 256 + wm * 128 + lq * 4;
    const int col0 = bn * 256 + wn * 64 + lr;

    const int seg = (EPI == EPI_QKV) ? (bn >> 2) : 0;   // 1024-col segments
    ushort_t* qkv_out = (EPI == EPI_QKV)
        ? (seg == 0 ? outB : (seg == 1 ? outB2 : outB3)) : outB;
    const float* qkv_bias = (EPI == EPI_QKV)
        ? (seg == 0 ? bias : (seg == 1 ? bias2 : bias3)) : bias;
    const int blen = (EPI == EPI_QKV) ? lens[bm >> 4] : 0;

    #pragma unroll
    for (int i = 0; i < 8; i++) {
        #pragma unroll
        for (int j = 0; j < 4; j++) {
            const int gn = col0 + j * 16;
            const float bsv = (EPI == EPI_QKV) ? qkv_bias[gn & 1023] : bias[gn];
            #pragma unroll
            for (int r = 0; r < 4; r++) {
                const int gm = row0 + i * 16 + r;
                float v = acc[i][j][r] + bsv;
                if (EPI == EPI_QKV) {
                    const size_t oi = (size_t)gm * DMODEL + (gn & 1023);
                    if (seg == 2) {
                        qkv_out[oi] = f2bf(v);                    // V
                    } else {
                        float e = v > 0.f ? v + 1.f : __expf(v);  // elu+1
                        if (seg == 1 && (gm & 4095) >= blen) e = 0.f;  // K mask
                        qkv_out[oi] = f2bf(e);
                    }
                } else if (EPI == EPI_RES) {
                    const size_t oi = (size_t)gm * N + gn;
                    outF[oi] = v + res[oi];
                } else {  // EPI_GELU
                    const size_t oi = (size_t)gm * N + gn;
                    outB[oi] = f2bf(gelu_f(v));
                }
            }
        }
    }
}

// ---------------------------------------------------------------------------
__global__ __launch_bounds__(256) void ksum_kernel(const ushort_t* __restrict__ K,
                                                   float* __restrict__ out) {
    const int blk = blockIdx.x;
    const int n = blk >> 4, cg = blk & 15;
    const int tx = threadIdx.x & 63, ty = threadIdx.x >> 6;
    const int col = cg * 64 + tx;
    const ushort_t* p = K + ((size_t)n * SEQ + ty * 1024) * DMODEL + col;
    float a = 0.f;
    for (int s = 0; s < 1024; s++) a += bf2f(p[(size_t)s * DMODEL]);
    __shared__ float red[4][64];
    red[ty][tx] = a;
    __syncthreads();
    if (ty == 0) out[n * DMODEL + col] = red[0][tx] + red[1][tx] + red[2][tx] + red[3][tx];
}

// ---------------------------------------------------------------------------
__global__ __launch_bounds__(256) void kv_part(const ushort_t* __restrict__ K,
                                               const ushort_t* __restrict__ V,
                                               float* __restrict__ part) {
    const int chunk = blockIdx.x, nh = blockIdx.y;
    const int n = nh >> 4, h = nh & 15;
    const int tid = threadIdx.x;
    const int tm = tid >> 4, td = tid & 15;
    __shared__ float Ks[16][68];
    __shared__ float Vs[16][68];
    float acc[4][4] = {};
    const int s0 = chunk * 512;
    for (int sb = 0; sb < 512; sb += 16) {
        __syncthreads();
        for (int idx = tid; idx < 1024; idx += 256) {
            const int r = idx >> 6, c = idx & 63;
            const size_t gpos = ((size_t)(n * SEQ + s0 + sb + r)) * DMODEL + h * HDIM + c;
            Ks[r][c] = bf2f(K[gpos]);
            Vs[r][c] = bf2f(V[gpos]);
        }
        __syncthreads();
        #pragma unroll
        for (int s = 0; s < 16; s++) {
            float kv[4], vv[4];
            #pragma unroll
            for (int j = 0; j < 4; j++) kv[j] = Ks[s][td * 4 + j];
            #pragma unroll
            for (int i = 0; i < 4; i++) vv[i] = Vs[s][tm * 4 + i];
            #pragma unroll
            for (int i = 0; i < 4; i++)
                #pragma unroll
                for (int j = 0; j < 4; j++)
                    acc[i][j] += vv[i] * kv[j];
        }
    }
    float* o = part + ((size_t)chunk * 64 + nh) * 4096;
    #pragma unroll
    for (int i = 0; i < 4; i++)
        #pragma unroll
        for (int j = 0; j < 4; j++)
            o[(tm * 4 + i) * 64 + td * 4 + j] = acc[i][j];
}

__global__ __launch_bounds__(256) void kv_reduce(const float* __restrict__ part,
                                                 float* __restrict__ KV) {
    const int gid = blockIdx.x * 256 + threadIdx.x;
    float a = 0.f;
    #pragma unroll
    for (int c = 0; c < 8; c++) a += part[(size_t)c * (64 * 4096) + gid];
    KV[gid] = a;
}

// ---------------------------------------------------------------------------
__global__ __launch_bounds__(256) void attn_kernel(const ushort_t* __restrict__ Q,
                                                   const float* __restrict__ KV,
                                                   const float* __restrict__ Ksum,
                                                   ushort_t* __restrict__ out) {
    const int bx = blockIdx.x, nh = blockIdx.y;
    const int n = nh >> 4, h = nh & 15;
    const int tid = threadIdx.x;
    const int ty = tid >> 4, tx = tid & 15;
    __shared__ float KVs[64][65];
    __shared__ float Qs[64][65];
    __shared__ float Zs[64];
    const int t0 = n * SEQ + bx * 64;
    for (int idx = tid; idx < 4096; idx += 256) {
        const int r = idx >> 6, c = idx & 63;
        KVs[r][c] = KV[(size_t)nh * 4096 + idx];
        Qs[r][c] = bf2f(Q[((size_t)(t0 + r)) * DMODEL + h * HDIM + c]);
    }
    __syncthreads();
    if (tid < 64) {
        const float* ks = Ksum + n * DMODEL + h * HDIM;
        float a = 0.f;
        #pragma unroll
        for (int d = 0; d < 64; d++) a += Qs[tid][d] * ks[d];
        Zs[tid] = 1.f / (a + 1e-6f);
    }
    __syncthreads();
    float acc[4][4] = {};
    for (int d = 0; d < 64; d++) {
        float qv[4], kv[4];
        #pragma unroll
        for (int i = 0; i < 4; i++) qv[i] = Qs[ty * 4 + i][d];
        #pragma unroll
        for (int j = 0; j < 4; j++) kv[j] = KVs[tx * 4 + j][d];
        #pragma unroll
        for (int i = 0; i < 4; i++)
            #pragma unroll
            for (int j = 0; j < 4; j++)
                acc[i][j] += qv[i] * kv[j];
    }
    #pragma unroll
    for (int i = 0; i < 4; i++) {
        const int r = ty * 4 + i;
        const float z = Zs[r];
        v4u o;
        #pragma unroll
        for (int j = 0; j < 4; j++) o[j] = f2bf(acc[i][j] * z);
        *(v4u*)&out[((size_t)(t0 + r)) * DMODEL + h * HDIM + tx * 4] = o;  // 8B store
    }
}

// ---------------------------------------------------------------------------
__global__ __launch_bounds__(256) void ln_kernel(const float* in, float* outF,
                                                 ushort_t* outB,
                                                 const float* __restrict__ g,
                                                 const float* __restrict__ b) {
    const int row = blockIdx.x;
    const int tid = threadIdx.x;
    const float4 v = ((const float4*)(in + (size_t)row * DMODEL))[tid];
    float s = v.x + v.y + v.z + v.w;
    float ss = v.x * v.x + v.y * v.y + v.z * v.z + v.w * v.w;
    #pragma unroll
    for (int off = 32; off; off >>= 1) {
        s += __shfl_down(s, off);
        ss += __shfl_down(ss, off);
    }
    __shared__ float red[8];
    const int lane = tid & 63, w = tid >> 6;
    if (lane == 0) { red[w * 2] = s; red[w * 2 + 1] = ss; }
    __syncthreads();
    s = red[0] + red[2] + red[4] + red[6];
    ss = red[1] + red[3] + red[5] + red[7];
    const float mu = s * (1.f / DMODEL);
    const float var = ss * (1.f / DMODEL) - mu * mu;
    const float rs = rsqrtf(var + 1e-5f);
    const float4 gg = ((const float4*)g)[tid];
    const float4 bb = ((const float4*)b)[tid];
    float4 o;
    o.x = (v.x - mu) * rs * gg.x + bb.x;
    o.y = (v.y - mu) * rs * gg.y + bb.y;
    o.z = (v.z - mu) * rs * gg.z + bb.z;
    o.w = (v.w - mu) * rs * gg.w + bb.w;
    ((float4*)(outF + (size_t)row * DMODEL))[tid] = o;
    if (outB) {
        v4u ob;
        ob[0] = f2bf(o.x); ob[1] = f2bf(o.y); ob[2] = f2bf(o.z); ob[3] = f2bf(o.w);
        *(v4u*)(outB + (size_t)row * DMODEL + tid * 4) = ob;
    }
}

// ---------------------------------------------------------------------------
extern "C" void kernel_launch(void* const* d_in, const int* in_sizes, int n_in,
                              void* d_out, int out_size, void* d_ws, size_t ws_size,
                              hipStream_t stream) {
    const float* src = (const float*)d_in[0];
    const unsigned char* mask = (const unsigned char*)d_in[1];
    const float* Wq = (const float*)d_in[2];
    const float* bq = (const float*)d_in[3];
    const float* Wk = (const float*)d_in[4];
    const float* bk = (const float*)d_in[5];
    const float* Wv = (const float*)d_in[6];
    const float* bv = (const float*)d_in[7];
    const float* Wo = (const float*)d_in[8];
    const float* bo = (const float*)d_in[9];
    const float* W1 = (const float*)d_in[10];
    const float* b1 = (const float*)d_in[11];
    const float* W2 = (const float*)d_in[12];
    const float* b2 = (const float*)d_in[13];
    const float* g1 = (const float*)d_in[14];
    const float* be1 = (const float*)d_in[15];
    const float* g2 = (const float*)d_in[16];
    const float* be2 = (const float*)d_in[17];

    float* xout = (float*)d_out;  // fp32 residual-stream master

    char* ws = (char*)d_ws;
    size_t off = 0;
    auto alloc = [&](size_t bytes) -> void* {
        void* p = (void*)(ws + off);
        off += (bytes + 255) & ~(size_t)255;
        return p;
    };
    const size_t DD = (size_t)DMODEL * DMODEL;
    const size_t FD = (size_t)DFF * DMODEL;
    const size_t MD = (size_t)MTOK * DMODEL;

    ushort_t* wqkv_bf = (ushort_t*)alloc(NLAYER * 3 * DD * 2);  // [L][3][D][D]
    ushort_t* wo_bf = (ushort_t*)alloc(NLAYER * DD * 2);
    ushort_t* w1r = (ushort_t*)alloc(FD * 2);
    ushort_t* w2r = (ushort_t*)alloc(FD * 2);
    ushort_t* xbf = (ushort_t*)alloc(MD * 2);
    ushort_t* Qb = (ushort_t*)alloc(MD * 2);
    ushort_t* Kb = (ushort_t*)alloc(MD * 2);
    ushort_t* Vb = (ushort_t*)alloc(MD * 2);
    (void)alloc(MD * 2);          // hb (=Qb) overlay spans MTOK*DFF bf16
    ushort_t* hb = Qb;
    float* Ksum = (float*)alloc((size_t)NBATCH * DMODEL * 4);
    float* KVp = (float*)alloc((size_t)8 * 64 * 4096 * 4);
    float* KVb = (float*)alloc((size_t)64 * 4096 * 4);
    int* lens = (int*)alloc(256);
    if (off > ws_size) return;

    cvt_qkv<<<dim3((unsigned)((NLAYER * DD) / 1024)), dim3(256), 0, stream>>>(Wq, Wk, Wv, wqkv_bf);
    cvt_bf16<<<dim3((unsigned)((NLAYER * DD) / 1024)), dim3(256), 0, stream>>>(Wo, wo_bf, (int)(NLAYER * DD));
    lens_kernel<<<dim3(1), dim3(256), 0, stream>>>(mask, lens);
    cvt_bf16<<<dim3((unsigned)(MD / 1024)), dim3(256), 0, stream>>>(src, xbf, (int)MD);

    const dim3 blk(256);
    const dim3 blkG(512);
    const dim3 gQKV((MTOK / 256) * (3 * DMODEL / 256));  // 768 blocks
    const dim3 gD((MTOK / 256) * (DMODEL / 256));        // 256 blocks
    const dim3 gF((MTOK / 256) * (DFF / 256));           // 1024 blocks

    for (int l = 0; l < NLAYER; l++) {
        const ushort_t* wqkvl = wqkv_bf + (size_t)l * 3 * DD;
        const ushort_t* wol = wo_bf + l * DD;
        const float* bql = bq + l * DMODEL;
        const float* bkl = bk + l * DMODEL;
        const float* bvl = bv + l * DMODEL;
        const float* bol = bo + l * DMODEL;
        const float* b1l = b1 + l * DFF;
        const float* b2l = b2 + l * DMODEL;
        const float* g1l = g1 + l * DMODEL;
        const float* be1l = be1 + l * DMODEL;
        const float* g2l = g2 + l * DMODEL;
        const float* be2l = be2 + l * DMODEL;
        const float* resx = (l == 0) ? src : xout;

        // fused Q/K/V projection with feature map + mask
        gemm_bt<EPI_QKV><<<gQKV, blkG, 0, stream>>>(xbf, wqkvl, bql, bkl, bvl,
            nullptr, lens, Qb, Kb, Vb, nullptr, MTOK, 3 * DMODEL, DMODEL);

        // linear-attention core
        ksum_kernel<<<dim3(64), blk, 0, stream>>>(Kb, Ksum);
        kv_part<<<dim3(8, 64), blk, 0, stream>>>(Kb, Vb, KVp);
        kv_reduce<<<dim3(64 * 4096 / 256), blk, 0, stream>>>(KVp, KVb);
        attn_kernel<<<dim3(64, 64), blk, 0, stream>>>(Qb, KVb, Ksum, Kb);  // attn -> Kb

        // output projection + residual (fp32), then LN1 + bf16 copy
        gemm_bt<EPI_RES><<<gD, blkG, 0, stream>>>(Kb, wol, bol, nullptr, nullptr,
            resx, lens, nullptr, nullptr, nullptr, xout, MTOK, DMODEL, DMODEL);
        ln_kernel<<<dim3(MTOK), blk, 0, stream>>>(xout, xout, xbf, g1l, be1l);

        // FFN
        cvt_bf16<<<dim3((unsigned)(FD / 1024)), blk, 0, stream>>>(W1 + l * FD, w1r, (int)FD);
        gemm_bt<EPI_GELU><<<gF, blkG, 0, stream>>>(xbf, w1r, b1l, nullptr, nullptr,
            nullptr, lens, hb, nullptr, nullptr, nullptr, MTOK, DFF, DMODEL);
        cvt_bf16<<<dim3((unsigned)(FD / 1024)), blk, 0, stream>>>(W2 + l * FD, w2r, (int)FD);
        gemm_bt<EPI_RES><<<gD, blkG, 0, stream>>>(hb, w2r, b2l, nullptr, nullptr,
            xout, lens, nullptr, nullptr, nullptr, xout, MTOK, DMODEL, DFF);
        ln_kernel<<<dim3(MTOK), blk, 0, stream>>>(xout, xout, (l == NLAYER - 1) ? nullptr : xbf, g2l, be2l);
    }
}